// Round 4
// baseline (519.607 us; speedup 1.0000x reference)
//
#include <hip/hip_runtime.h>

// GCN graph classifier: 3x GCNConv(64->64, relu) + mean-pool + linear(64->10)
// N=100000 nodes, E=1600000 edges, 64 graphs.
//
// R3 -> R4: fill_kernel was 110us with WRITE_SIZE=108MB for 6.4MB of col[]
// payload (every scattered 4B store dirtied+evicted a 64B line; working set
// > per-XCD L2). Replaced by 8 segmented passes: each pass scatters only
// edges whose dst is in a 1/8 node-range, so the active col window (0.8MB)
// is L2-resident and lines are fully populated before writeback. Re-reading
// dst 8x is cheap streaming traffic (~51MB).

#define HIDDEN 64
#define NSEG 8

__global__ void hist_kernel(const int* __restrict__ dst, int* __restrict__ cnt, int E) {
    int e4 = blockIdx.x * blockDim.x + threadIdx.x;
    if (e4 * 4 + 3 < E) {
        int4 d = reinterpret_cast<const int4*>(dst)[e4];
        atomicAdd(&cnt[d.x], 1);
        atomicAdd(&cnt[d.y], 1);
        atomicAdd(&cnt[d.z], 1);
        atomicAdd(&cnt[d.w], 1);
    } else {
        for (int e = e4 * 4; e < E; e++) atomicAdd(&cnt[dst[e]], 1);
    }
}

__global__ void dinv_kernel(const int* __restrict__ cnt, float* __restrict__ dinv, int N) {
    int n = blockIdx.x * blockDim.x + threadIdx.x;
    if (n < N) dinv[n] = 1.0f / sqrtf((float)(cnt[n] + 1));  // +1 self loop
}

__global__ __launch_bounds__(1024) void scan_chunk_sums(const int* __restrict__ cnt,
                                                        int* __restrict__ chunkSums, int N) {
    __shared__ int s[1024];
    int i = blockIdx.x * 1024 + threadIdx.x;
    s[threadIdx.x] = (i < N) ? cnt[i] : 0;
    __syncthreads();
    for (int off = 512; off > 0; off >>= 1) {
        if (threadIdx.x < off) s[threadIdx.x] += s[threadIdx.x + off];
        __syncthreads();
    }
    if (threadIdx.x == 0) chunkSums[blockIdx.x] = s[0];
}

__global__ void scan_offsets(int* __restrict__ chunkSums, int nChunks) {
    if (threadIdx.x == 0 && blockIdx.x == 0) {
        int acc = 0;
        for (int i = 0; i < nChunks; i++) { int v = chunkSums[i]; chunkSums[i] = acc; acc += v; }
    }
}

__global__ __launch_bounds__(1024) void scan_write(const int* __restrict__ cnt,
                                                   const int* __restrict__ chunkOffs,
                                                   int* __restrict__ rowptr, int N, int E) {
    __shared__ int s[1024];
    int i = blockIdx.x * 1024 + threadIdx.x;
    int v = (i < N) ? cnt[i] : 0;
    s[threadIdx.x] = v;
    __syncthreads();
    for (int off = 1; off < 1024; off <<= 1) {
        int t = (threadIdx.x >= off) ? s[threadIdx.x - off] : 0;
        __syncthreads();
        s[threadIdx.x] += t;
        __syncthreads();
    }
    int base = chunkOffs[blockIdx.x];
    if (i < N) rowptr[i] = base + s[threadIdx.x] - v;      // exclusive scan
    if (i == N - 1) rowptr[N] = base + s[threadIdx.x];     // total == E
}

// One pass of the segmented CSR fill: only edges with dst in [lo,hi) scatter.
__global__ void fill_seg_kernel(const int* __restrict__ src, const int* __restrict__ dst,
                                const int* __restrict__ rowptr, int* __restrict__ cursor,
                                int* __restrict__ col, int E, int lo, int hi) {
    int e4 = blockIdx.x * blockDim.x + threadIdx.x;
    int base = e4 * 4;
    if (base + 3 < E) {
        int4 d = reinterpret_cast<const int4*>(dst)[e4];
        if (d.x >= lo && d.x < hi) col[rowptr[d.x] + atomicAdd(&cursor[d.x], 1)] = src[base];
        if (d.y >= lo && d.y < hi) col[rowptr[d.y] + atomicAdd(&cursor[d.y], 1)] = src[base + 1];
        if (d.z >= lo && d.z < hi) col[rowptr[d.z] + atomicAdd(&cursor[d.z], 1)] = src[base + 2];
        if (d.w >= lo && d.w < hi) col[rowptr[d.w] + atomicAdd(&cursor[d.w], 1)] = src[base + 3];
    } else {
        for (int e = base; e < E; e++) {
            int d = dst[e];
            if (d >= lo && d < hi) col[rowptr[d] + atomicAdd(&cursor[d], 1)] = src[e];
        }
    }
}

// Hs = dinv[row] * (X @ W)  (X:[N,64], W:[64,64] row-major, staged in LDS).
__global__ __launch_bounds__(256) void gemm64(const float* __restrict__ X,
                                              const float* __restrict__ W,
                                              const float* __restrict__ dinv,
                                              float* __restrict__ Hs, int N) {
    __shared__ float Ws[64 * 64];
    for (int i = threadIdx.x; i < 64 * 64; i += 256) Ws[i] = W[i];
    __syncthreads();
    int row = blockIdx.x * 256 + threadIdx.x;
    if (row >= N) return;
    const float4* xr = reinterpret_cast<const float4*>(X + (size_t)row * 64);
    const float4* Ws4 = reinterpret_cast<const float4*>(Ws);
    float4 acc[16];
#pragma unroll
    for (int j = 0; j < 16; j++) acc[j] = make_float4(0.f, 0.f, 0.f, 0.f);
#pragma unroll
    for (int k4 = 0; k4 < 16; k4++) {
        float4 xv = xr[k4];
#pragma unroll
        for (int kk = 0; kk < 4; kk++) {
            float xk = (&xv.x)[kk];
            int k = k4 * 4 + kk;
#pragma unroll
            for (int j = 0; j < 16; j++) {
                float4 w = Ws4[k * 16 + j];
                acc[j].x += xk * w.x;
                acc[j].y += xk * w.y;
                acc[j].z += xk * w.z;
                acc[j].w += xk * w.w;
            }
        }
    }
    float dn = dinv[row];
    float4* hr = reinterpret_cast<float4*>(Hs + (size_t)row * 64);
#pragma unroll
    for (int j = 0; j < 16; j++)
        hr[j] = make_float4(dn * acc[j].x, dn * acc[j].y, dn * acc[j].z, dn * acc[j].w);
}

// out[n,:] = relu( dinv[n] * (sum_e Hs[col[e],:] + Hs[n,:]) + b )
// One wave per node; lane = channel; 8 independent row gathers in flight.
__global__ __launch_bounds__(256) void aggregate_kernel(const float* __restrict__ Hs,
                                                        const int* __restrict__ rowptr,
                                                        const int* __restrict__ col,
                                                        const float* __restrict__ dinv,
                                                        const float* __restrict__ bias,
                                                        float* __restrict__ OUT, int N) {
    int node = blockIdx.x * 4 + (threadIdx.x >> 6);
    int lane = threadIdx.x & 63;
    if (node >= N) return;
    int beg = __builtin_amdgcn_readfirstlane(rowptr[node]);
    int end = __builtin_amdgcn_readfirstlane(rowptr[node + 1]);
    float a0 = 0.f, a1 = 0.f, a2 = 0.f, a3 = 0.f;
    float a4 = 0.f, a5 = 0.f, a6 = 0.f, a7 = 0.f;
    int e = beg;
    for (; e + 8 <= end; e += 8) {
        int s0 = col[e],     s1 = col[e + 1], s2 = col[e + 2], s3 = col[e + 3];
        int s4 = col[e + 4], s5 = col[e + 5], s6 = col[e + 6], s7 = col[e + 7];
        a0 += Hs[(size_t)s0 * 64 + lane];
        a1 += Hs[(size_t)s1 * 64 + lane];
        a2 += Hs[(size_t)s2 * 64 + lane];
        a3 += Hs[(size_t)s3 * 64 + lane];
        a4 += Hs[(size_t)s4 * 64 + lane];
        a5 += Hs[(size_t)s5 * 64 + lane];
        a6 += Hs[(size_t)s6 * 64 + lane];
        a7 += Hs[(size_t)s7 * 64 + lane];
    }
    for (; e < end; e++) a0 += Hs[(size_t)col[e] * 64 + lane];
    float acc = ((a0 + a1) + (a2 + a3)) + ((a4 + a5) + (a6 + a7));
    acc += Hs[(size_t)node * 64 + lane];                 // self loop (pre-scaled)
    acc = fmaxf(acc * dinv[node] + bias[lane], 0.f);
    OUT[(size_t)node * 64 + lane] = acc;
}

// One wave per 64 contiguous nodes; batch sorted -> few graph boundaries.
__global__ __launch_bounds__(256) void pool_partial(const float* __restrict__ H,
                                                    const int* __restrict__ batch,
                                                    float* __restrict__ sums, int N) {
    int wid = (blockIdx.x * blockDim.x + threadIdx.x) >> 6;
    int lane = threadIdx.x & 63;
    int start = wid * 64;
    if (start >= N) return;
    int end = min(start + 64, N);
    int g = batch[start];
    float acc = 0.f;
    for (int n = start; n < end; n++) {
        int bg = batch[n];
        if (bg != g) { atomicAdd(&sums[g * 64 + lane], acc); acc = 0.f; g = bg; }
        acc += H[(size_t)n * 64 + lane];
    }
    atomicAdd(&sums[g * 64 + lane], acc);
}

__device__ __forceinline__ int lower_bound_dev(const int* a, int n, int key) {
    int lo = 0, hi = n;
    while (lo < hi) { int mid = (lo + hi) >> 1; if (a[mid] < key) lo = mid + 1; else hi = mid; }
    return lo;
}

// out[g,c] = (sum_k sums[g,k]*Wc[k,c]) / cnt[g] + bc[c]
__global__ void classify_kernel(const float* __restrict__ sums, const float* __restrict__ Wc,
                                const float* __restrict__ bc, const int* __restrict__ batch,
                                float* __restrict__ out, int N) {
    int t = blockIdx.x * blockDim.x + threadIdx.x;
    if (t >= 64 * 10) return;
    int g = t / 10, c = t % 10;
    float acc = 0.f;
    for (int k = 0; k < 64; k++) acc += sums[g * 64 + k] * Wc[k * 10 + c];
    int cnt = lower_bound_dev(batch, N, g + 1) - lower_bound_dev(batch, N, g);
    out[t] = acc / (float)max(cnt, 1) + bc[c];
}

extern "C" void kernel_launch(void* const* d_in, const int* in_sizes, int n_in,
                              void* d_out, int out_size, void* d_ws, size_t ws_size,
                              hipStream_t stream) {
    const float* x  = (const float*)d_in[0];
    const int* ei   = (const int*)d_in[1];
    const int* batch= (const int*)d_in[2];
    const float* W1 = (const float*)d_in[3];
    const float* b1 = (const float*)d_in[4];
    const float* W2 = (const float*)d_in[5];
    const float* b2 = (const float*)d_in[6];
    const float* W3 = (const float*)d_in[7];
    const float* b3 = (const float*)d_in[8];
    const float* Wc = (const float*)d_in[9];
    const float* bc = (const float*)d_in[10];

    int N = in_sizes[0] / HIDDEN;
    int E = in_sizes[1] / 2;
    const int* src = ei;
    const int* dst = ei + E;

    char* ws = (char*)d_ws;
    size_t off = 0;
    auto alloc = [&](size_t bytes) { void* p = ws + off; off = (off + bytes + 255) & ~(size_t)255; return p; };
    int*   cnt       = (int*)  alloc((size_t)N * 4);        // histogram, then cursor
    float* dinv      = (float*)alloc((size_t)N * 4);
    int*   rowptr    = (int*)  alloc((size_t)(N + 1) * 4);
    int*   chunkSums = (int*)  alloc(1024);
    int*   col       = (int*)  alloc((size_t)E * 4);
    float* h0        = (float*)alloc((size_t)N * HIDDEN * 4);
    float* h1        = (float*)alloc((size_t)N * HIDDEN * 4);
    float* sums      = (float*)alloc(64 * 64 * 4);

    // ---- CSR build ----
    hipMemsetAsync(cnt, 0, (size_t)N * 4, stream);
    hist_kernel<<<((E + 3) / 4 + 255) / 256, 256, 0, stream>>>(dst, cnt, E);
    dinv_kernel<<<(N + 255) / 256, 256, 0, stream>>>(cnt, dinv, N);
    int nChunks = (N + 1023) / 1024;
    scan_chunk_sums<<<nChunks, 1024, 0, stream>>>(cnt, chunkSums, N);
    scan_offsets<<<1, 64, 0, stream>>>(chunkSums, nChunks);
    scan_write<<<nChunks, 1024, 0, stream>>>(cnt, chunkSums, rowptr, N, E);
    hipMemsetAsync(cnt, 0, (size_t)N * 4, stream);
    int gFill = ((E + 3) / 4 + 255) / 256;
    int segSize = (N + NSEG - 1) / NSEG;
    for (int s = 0; s < NSEG; s++) {
        int lo = s * segSize;
        int hi = min(lo + segSize, N);
        fill_seg_kernel<<<gFill, 256, 0, stream>>>(src, dst, rowptr, cnt, col, E, lo, hi);
    }

    // ---- 3 GCN layers ----
    int gGemm = (N + 255) / 256;
    int gAgg  = (N + 3) / 4;
    gemm64<<<gGemm, 256, 0, stream>>>(x, W1, dinv, h0, N);
    aggregate_kernel<<<gAgg, 256, 0, stream>>>(h0, rowptr, col, dinv, b1, h1, N);
    gemm64<<<gGemm, 256, 0, stream>>>(h1, W2, dinv, h0, N);
    aggregate_kernel<<<gAgg, 256, 0, stream>>>(h0, rowptr, col, dinv, b2, h1, N);
    gemm64<<<gGemm, 256, 0, stream>>>(h1, W3, dinv, h0, N);
    aggregate_kernel<<<gAgg, 256, 0, stream>>>(h0, rowptr, col, dinv, b3, h1, N);

    // ---- pool + classify ----
    hipMemsetAsync(sums, 0, 64 * 64 * 4, stream);
    pool_partial<<<(N + 255) / 256, 256, 0, stream>>>(h1, batch, sums, N);
    classify_kernel<<<1, 640, 0, stream>>>(sums, Wc, bc, batch, (float*)d_out, N);
}

// Round 5
// 367.128 us; speedup vs baseline: 1.4153x; 1.4153x over previous
//
#include <hip/hip_runtime.h>

// GCN graph classifier: 3x GCNConv(64->64, relu) + mean-pool + linear(64->10)
// N=100000 nodes, E=1600000 edges, 64 graphs.
//
// R4 -> R5: CSR build rewritten as a 2-level counting sort. Old hist+fill
// cost ~190us because every scattered 4B store/atomic costs ~32B of fabric
// write (hist: 1.6M atomics = 50MB WRITE; fill: 3.2M ops = 108MB). New:
//  1. bucket_count: LDS hist of 391 buckets (256 nodes each), 1 global
//     atomic per bucket per block.
//  2. bucket_scan: 1-block exclusive scan -> bucket bases.
//  3. bucket_scatter: per-block bucket reservation + packed 4B records
//     ((src<<8)|local_dst) written in ~64B dense runs.
//  4. bucket_build: 1 block/bucket; LDS node-hist + scan -> rowptr, dinv
//     (coalesced) + col scatter confined to a 16KB window (sector-dense).
// Replaces hist/dinv/scan/fill kernels entirely.

#define HIDDEN 64
#define BSHIFT 8          // 256 nodes per bucket
#define MAXB 512          // LDS histogram capacity (NB = ceil(N/256) = 391)

__global__ __launch_bounds__(256) void bucket_count(const int* __restrict__ dst,
                                                    int* __restrict__ gCount,
                                                    int E, int perBlock) {
    __shared__ int hist[MAXB];
    for (int i = threadIdx.x; i < MAXB; i += 256) hist[i] = 0;
    __syncthreads();
    int beg = blockIdx.x * perBlock;
    int end = min(beg + perBlock, E);
    if (beg < end) {
        int n4 = (end - beg) >> 2;
        const int4* d4 = reinterpret_cast<const int4*>(dst + beg);
        for (int g = threadIdx.x; g < n4; g += 256) {
            int4 d = d4[g];
            atomicAdd(&hist[d.x >> BSHIFT], 1);
            atomicAdd(&hist[d.y >> BSHIFT], 1);
            atomicAdd(&hist[d.z >> BSHIFT], 1);
            atomicAdd(&hist[d.w >> BSHIFT], 1);
        }
        for (int e = beg + (n4 << 2) + threadIdx.x; e < end; e += 256)
            atomicAdd(&hist[dst[e] >> BSHIFT], 1);
    }
    __syncthreads();
    for (int i = threadIdx.x; i < MAXB; i += 256)
        if (hist[i]) atomicAdd(&gCount[i], hist[i]);
}

__global__ __launch_bounds__(512) void bucket_scan(const int* __restrict__ gCount,
                                                   int* __restrict__ gBase,
                                                   int* __restrict__ gCursor,
                                                   int* __restrict__ rowptr,
                                                   int NB, int N, int E) {
    __shared__ int sc[512];
    int t = threadIdx.x;
    int v = (t < NB) ? gCount[t] : 0;
    sc[t] = v;
    __syncthreads();
    for (int off = 1; off < 512; off <<= 1) {
        int u = (t >= off) ? sc[t - off] : 0;
        __syncthreads();
        sc[t] += u;
        __syncthreads();
    }
    if (t < NB) { int b = sc[t] - v; gBase[t] = b; gCursor[t] = b; }
    if (t == 0) rowptr[N] = E;
}

// Packed record: (src << 8) | (dst & 255). src < 2^24 required (N=100000 ok).
__global__ __launch_bounds__(256) void bucket_scatter(const int* __restrict__ src,
                                                      const int* __restrict__ dst,
                                                      int* __restrict__ gCursor,
                                                      unsigned* __restrict__ rec,
                                                      int E, int perBlock) {
    __shared__ int hist[MAXB];
    __shared__ int cur[MAXB];
    for (int i = threadIdx.x; i < MAXB; i += 256) hist[i] = 0;
    __syncthreads();
    int beg = blockIdx.x * perBlock;
    int end = min(beg + perBlock, E);
    if (beg >= end) return;
    int n4 = (end - beg) >> 2;
    const int4* d4 = reinterpret_cast<const int4*>(dst + beg);
    const int4* s4 = reinterpret_cast<const int4*>(src + beg);
    for (int g = threadIdx.x; g < n4; g += 256) {
        int4 d = d4[g];
        atomicAdd(&hist[d.x >> BSHIFT], 1);
        atomicAdd(&hist[d.y >> BSHIFT], 1);
        atomicAdd(&hist[d.z >> BSHIFT], 1);
        atomicAdd(&hist[d.w >> BSHIFT], 1);
    }
    for (int e = beg + (n4 << 2) + threadIdx.x; e < end; e += 256)
        atomicAdd(&hist[dst[e] >> BSHIFT], 1);
    __syncthreads();
    for (int i = threadIdx.x; i < MAXB; i += 256)
        cur[i] = hist[i] ? atomicAdd(&gCursor[i], hist[i]) : 0;
    __syncthreads();
    for (int g = threadIdx.x; g < n4; g += 256) {
        int4 d = d4[g];
        int4 s = s4[g];
        int p;
        p = atomicAdd(&cur[d.x >> BSHIFT], 1); rec[p] = ((unsigned)s.x << 8) | (unsigned)(d.x & 255);
        p = atomicAdd(&cur[d.y >> BSHIFT], 1); rec[p] = ((unsigned)s.y << 8) | (unsigned)(d.y & 255);
        p = atomicAdd(&cur[d.z >> BSHIFT], 1); rec[p] = ((unsigned)s.z << 8) | (unsigned)(d.z & 255);
        p = atomicAdd(&cur[d.w >> BSHIFT], 1); rec[p] = ((unsigned)s.w << 8) | (unsigned)(d.w & 255);
    }
    for (int e = beg + (n4 << 2) + threadIdx.x; e < end; e += 256) {
        int d = dst[e];
        int p = atomicAdd(&cur[d >> BSHIFT], 1);
        rec[p] = ((unsigned)src[e] << 8) | (unsigned)(d & 255);
    }
}

// One block per bucket: local node histogram + scan -> rowptr/dinv (coalesced),
// then col scatter confined to this bucket's 16KB window.
__global__ __launch_bounds__(256) void bucket_build(const unsigned* __restrict__ rec,
                                                    const int* __restrict__ gBase,
                                                    const int* __restrict__ gCount,
                                                    int* __restrict__ rowptr,
                                                    float* __restrict__ dinv,
                                                    int* __restrict__ col, int N) {
    int b = blockIdx.x;
    int base = gBase[b], cnt = gCount[b];
    int t = threadIdx.x;
    __shared__ int hist[256];
    __shared__ int sc[256];
    __shared__ int cur[256];
    hist[t] = 0;
    __syncthreads();
    for (int i = base + t; i < base + cnt; i += 256)
        atomicAdd(&hist[rec[i] & 255], 1);
    __syncthreads();
    int myCnt = hist[t];
    sc[t] = myCnt;
    __syncthreads();
    for (int off = 1; off < 256; off <<= 1) {
        int u = (t >= off) ? sc[t - off] : 0;
        __syncthreads();
        sc[t] += u;
        __syncthreads();
    }
    int nodeBase = base + sc[t] - myCnt;   // exclusive
    int node = (b << BSHIFT) + t;
    if (node < N) {
        rowptr[node] = nodeBase;
        dinv[node] = rsqrtf((float)(myCnt + 1));
    }
    cur[t] = nodeBase;
    __syncthreads();
    for (int i = base + t; i < base + cnt; i += 256) {
        unsigned r = rec[i];
        int p = atomicAdd(&cur[r & 255], 1);
        col[p] = (int)(r >> 8);
    }
}

// Hs = dinv[row] * (X @ W)  (X:[N,64], W:[64,64] row-major, staged in LDS).
__global__ __launch_bounds__(256) void gemm64(const float* __restrict__ X,
                                              const float* __restrict__ W,
                                              const float* __restrict__ dinv,
                                              float* __restrict__ Hs, int N) {
    __shared__ float Ws[64 * 64];
    for (int i = threadIdx.x; i < 64 * 64; i += 256) Ws[i] = W[i];
    __syncthreads();
    int row = blockIdx.x * 256 + threadIdx.x;
    if (row >= N) return;
    const float4* xr = reinterpret_cast<const float4*>(X + (size_t)row * 64);
    const float4* Ws4 = reinterpret_cast<const float4*>(Ws);
    float4 acc[16];
#pragma unroll
    for (int j = 0; j < 16; j++) acc[j] = make_float4(0.f, 0.f, 0.f, 0.f);
#pragma unroll
    for (int k4 = 0; k4 < 16; k4++) {
        float4 xv = xr[k4];
#pragma unroll
        for (int kk = 0; kk < 4; kk++) {
            float xk = (&xv.x)[kk];
            int k = k4 * 4 + kk;
#pragma unroll
            for (int j = 0; j < 16; j++) {
                float4 w = Ws4[k * 16 + j];
                acc[j].x += xk * w.x;
                acc[j].y += xk * w.y;
                acc[j].z += xk * w.z;
                acc[j].w += xk * w.w;
            }
        }
    }
    float dn = dinv[row];
    float4* hr = reinterpret_cast<float4*>(Hs + (size_t)row * 64);
#pragma unroll
    for (int j = 0; j < 16; j++)
        hr[j] = make_float4(dn * acc[j].x, dn * acc[j].y, dn * acc[j].z, dn * acc[j].w);
}

// out[n,:] = relu( dinv[n] * (sum_e Hs[col[e],:] + Hs[n,:]) + b )
// One wave per node; lane = channel; 8 independent row gathers in flight.
__global__ __launch_bounds__(256) void aggregate_kernel(const float* __restrict__ Hs,
                                                        const int* __restrict__ rowptr,
                                                        const int* __restrict__ col,
                                                        const float* __restrict__ dinv,
                                                        const float* __restrict__ bias,
                                                        float* __restrict__ OUT, int N) {
    int node = blockIdx.x * 4 + (threadIdx.x >> 6);
    int lane = threadIdx.x & 63;
    if (node >= N) return;
    int beg = __builtin_amdgcn_readfirstlane(rowptr[node]);
    int end = __builtin_amdgcn_readfirstlane(rowptr[node + 1]);
    float a0 = 0.f, a1 = 0.f, a2 = 0.f, a3 = 0.f;
    float a4 = 0.f, a5 = 0.f, a6 = 0.f, a7 = 0.f;
    int e = beg;
    for (; e + 8 <= end; e += 8) {
        int s0 = col[e],     s1 = col[e + 1], s2 = col[e + 2], s3 = col[e + 3];
        int s4 = col[e + 4], s5 = col[e + 5], s6 = col[e + 6], s7 = col[e + 7];
        a0 += Hs[(size_t)s0 * 64 + lane];
        a1 += Hs[(size_t)s1 * 64 + lane];
        a2 += Hs[(size_t)s2 * 64 + lane];
        a3 += Hs[(size_t)s3 * 64 + lane];
        a4 += Hs[(size_t)s4 * 64 + lane];
        a5 += Hs[(size_t)s5 * 64 + lane];
        a6 += Hs[(size_t)s6 * 64 + lane];
        a7 += Hs[(size_t)s7 * 64 + lane];
    }
    for (; e < end; e++) a0 += Hs[(size_t)col[e] * 64 + lane];
    float acc = ((a0 + a1) + (a2 + a3)) + ((a4 + a5) + (a6 + a7));
    acc += Hs[(size_t)node * 64 + lane];                 // self loop (pre-scaled)
    acc = fmaxf(acc * dinv[node] + bias[lane], 0.f);
    OUT[(size_t)node * 64 + lane] = acc;
}

// One wave per 64 contiguous nodes; batch sorted -> few graph boundaries.
__global__ __launch_bounds__(256) void pool_partial(const float* __restrict__ H,
                                                    const int* __restrict__ batch,
                                                    float* __restrict__ sums, int N) {
    int wid = (blockIdx.x * blockDim.x + threadIdx.x) >> 6;
    int lane = threadIdx.x & 63;
    int start = wid * 64;
    if (start >= N) return;
    int end = min(start + 64, N);
    int g = batch[start];
    float acc = 0.f;
    for (int n = start; n < end; n++) {
        int bg = batch[n];
        if (bg != g) { atomicAdd(&sums[g * 64 + lane], acc); acc = 0.f; g = bg; }
        acc += H[(size_t)n * 64 + lane];
    }
    atomicAdd(&sums[g * 64 + lane], acc);
}

__device__ __forceinline__ int lower_bound_dev(const int* a, int n, int key) {
    int lo = 0, hi = n;
    while (lo < hi) { int mid = (lo + hi) >> 1; if (a[mid] < key) lo = mid + 1; else hi = mid; }
    return lo;
}

// out[g,c] = (sum_k sums[g,k]*Wc[k,c]) / cnt[g] + bc[c]
__global__ void classify_kernel(const float* __restrict__ sums, const float* __restrict__ Wc,
                                const float* __restrict__ bc, const int* __restrict__ batch,
                                float* __restrict__ out, int N) {
    int t = blockIdx.x * blockDim.x + threadIdx.x;
    if (t >= 64 * 10) return;
    int g = t / 10, c = t % 10;
    float acc = 0.f;
    for (int k = 0; k < 64; k++) acc += sums[g * 64 + k] * Wc[k * 10 + c];
    int cnt = lower_bound_dev(batch, N, g + 1) - lower_bound_dev(batch, N, g);
    out[t] = acc / (float)max(cnt, 1) + bc[c];
}

extern "C" void kernel_launch(void* const* d_in, const int* in_sizes, int n_in,
                              void* d_out, int out_size, void* d_ws, size_t ws_size,
                              hipStream_t stream) {
    const float* x  = (const float*)d_in[0];
    const int* ei   = (const int*)d_in[1];
    const int* batch= (const int*)d_in[2];
    const float* W1 = (const float*)d_in[3];
    const float* b1 = (const float*)d_in[4];
    const float* W2 = (const float*)d_in[5];
    const float* b2 = (const float*)d_in[6];
    const float* W3 = (const float*)d_in[7];
    const float* b3 = (const float*)d_in[8];
    const float* Wc = (const float*)d_in[9];
    const float* bc = (const float*)d_in[10];

    int N = in_sizes[0] / HIDDEN;
    int E = in_sizes[1] / 2;
    const int* src = ei;
    const int* dst = ei + E;
    int NB = (N + 255) >> 8;              // buckets of 256 nodes (<= MAXB)

    char* ws = (char*)d_ws;
    size_t off = 0;
    auto alloc = [&](size_t bytes) { void* p = ws + off; off = (off + bytes + 255) & ~(size_t)255; return p; };
    int*   gCount = (int*)  alloc((size_t)MAXB * 4);
    int*   gBase  = (int*)  alloc((size_t)MAXB * 4);
    int*   gCursor= (int*)  alloc((size_t)MAXB * 4);
    int*   rowptr = (int*)  alloc((size_t)(N + 1) * 4);
    float* dinv   = (float*)alloc((size_t)N * 4);
    int*   col    = (int*)  alloc((size_t)E * 4);
    float* h0     = (float*)alloc((size_t)N * HIDDEN * 4);
    float* h1     = (float*)alloc((size_t)N * HIDDEN * 4);
    float* sums   = (float*)alloc(64 * 64 * 4);
    unsigned* rec = (unsigned*)h0;        // aliased: consumed before gemm1 writes h0

    // ---- CSR build (2-level counting sort) ----
    int grid = 256;
    int perBlock = (((E + grid - 1) / grid) + 3) & ~3;
    hipMemsetAsync(gCount, 0, (size_t)MAXB * 4, stream);
    hipMemsetAsync(sums, 0, 64 * 64 * 4, stream);
    bucket_count<<<grid, 256, 0, stream>>>(dst, gCount, E, perBlock);
    bucket_scan<<<1, 512, 0, stream>>>(gCount, gBase, gCursor, rowptr, NB, N, E);
    bucket_scatter<<<grid, 256, 0, stream>>>(src, dst, gCursor, rec, E, perBlock);
    bucket_build<<<NB, 256, 0, stream>>>(rec, gBase, gCount, rowptr, dinv, col, N);

    // ---- 3 GCN layers ----
    int gGemm = (N + 255) / 256;
    int gAgg  = (N + 3) / 4;
    gemm64<<<gGemm, 256, 0, stream>>>(x, W1, dinv, h0, N);
    aggregate_kernel<<<gAgg, 256, 0, stream>>>(h0, rowptr, col, dinv, b1, h1, N);
    gemm64<<<gGemm, 256, 0, stream>>>(h1, W2, dinv, h0, N);
    aggregate_kernel<<<gAgg, 256, 0, stream>>>(h0, rowptr, col, dinv, b2, h1, N);
    gemm64<<<gGemm, 256, 0, stream>>>(h1, W3, dinv, h0, N);
    aggregate_kernel<<<gAgg, 256, 0, stream>>>(h0, rowptr, col, dinv, b3, h1, N);

    // ---- pool + classify ----
    pool_partial<<<(N + 255) / 256, 256, 0, stream>>>(h1, batch, sums, N);
    classify_kernel<<<1, 640, 0, stream>>>(sums, Wc, bc, batch, (float*)d_out, N);
}